// Round 15
// baseline (315.399 us; speedup 1.0000x reference)
//
#include <hip/hip_runtime.h>
#include <hip/hip_bf16.h>
#include <hip/hip_fp16.h>

#define N_NODES 10000
#define N_EDGES 160000
#define N_E2    (N_EDGES + N_NODES)   // with self-loops
#define DIM     64
#define HD      256                    // HEADS * DIM
#define N_PRED  2
#define N_CLASS 16
#define N_STEPS 4
#define BUCKET  64                     // fixed CSR bucket per node; P(deg>64) ~ 1e-16

typedef __hip_bfloat16 bf16;
__device__ __forceinline__ float b2f(bf16 v) { return __bfloat162float(v); }
__device__ __forceinline__ int clampn(int v) { return v < 0 ? 0 : (v >= N_NODES ? N_NODES - 1 : v); }

typedef _Float16 h2_t __attribute__((ext_vector_type(2)));

// fp16 pair dot with fp32 accumulate (v_dot2_f32_f16)
__device__ __forceinline__ float dot2(unsigned int a, unsigned int b, float c) {
#if __has_builtin(__builtin_amdgcn_fdot2)
    h2_t av, bv;
    __builtin_memcpy(&av, &a, 4);
    __builtin_memcpy(&bv, &b, 4);
    return __builtin_amdgcn_fdot2(av, bv, c, false);
#else
    __half2 ah = *(__half2*)&a, bh = *(__half2*)&b;
    float2 af = __half22float2(ah), bf = __half22float2(bh);
    return c + af.x * bf.x + af.y * bf.y;
#endif
}

struct ConvTable {
    const void* src[17];
    int start[18];
};

__device__ __forceinline__ float loadf(const void* p, int idx, int isbf16) {
    return isbf16 ? b2f(((const bf16*)p)[idx]) : ((const float*)p)[idx];
}

// ---------------- dispatch 1: dtype detection + zero cursor ----------------
__global__ void detect_kernel(const unsigned int* __restrict__ e32,
                              const unsigned short* __restrict__ x16,
                              int* __restrict__ flags, int* __restrict__ cursor) {
    int i = blockIdx.x * 256 + threadIdx.x;
    if (i < N_NODES) cursor[i] = 0;
    if (blockIdx.x != 0) return;
    __shared__ int ce, cf;
    if (threadIdx.x == 0) { ce = 0; cf = 0; }
    __syncthreads();
    int le = 0;
    for (int k = threadIdx.x; k < 2048; k += 256)
        le += (e32[2 * k + 1] != 0u) ? 1 : 0;
    int lf = 0;
    for (int k = threadIdx.x; k < 1024; k += 256) {
        unsigned short u = x16[2 * k];
        int ex = (u >> 7) & 0xFF;
        lf += (u == 0 || (ex >= 114 && ex <= 141)) ? 1 : 0;
    }
    atomicAdd(&ce, le);
    atomicAdd(&cf, lf);
    __syncthreads();
    if (threadIdx.x == 0) {
        flags[0] = (ce < 1024) ? 1 : 0;   // edge_index is int64
        flags[1] = (cf >= 512) ? 1 : 0;   // floats are bf16
    }
}

// ---------------- dispatch 2: convert || pack || bucket-scatter ----------------
struct PreArgs {
    ConvTable tab;
    const void* Wl_raw; const void* Wr_raw; const void* W1_raw; const void* W2_raw;
    const int* edges;
    int cb, pb;          // block counts: convert, pack
};

__global__ void pre_kernel(PreArgs a, const int* __restrict__ flags,
                           float* __restrict__ xf, __half* __restrict__ wp,
                           int* __restrict__ cursor, int* __restrict__ csr_src) {
    const int b = blockIdx.x, t = threadIdx.x;
    const int isb = flags[1];
    if (b < a.cb) {
        int i = b * 256 + t;
        if (i >= a.tab.start[17]) return;
        int j = 0;
        #pragma unroll
        for (int k = 1; k < 17; ++k) j += (i >= a.tab.start[k]) ? 1 : 0;
        xf[i] = loadf(a.tab.src[j], i - a.tab.start[j], isb);
    } else if (b < a.cb + a.pb) {
        int i = (b - a.cb) * 256 + t;
        if (i >= 26624) return;
        const void* base; int width, loc;
        if (i < 8192)       { loc = i;         base = a.Wl_raw; width = 256; }
        else if (i < 16384) { loc = i - 8192;  base = a.Wr_raw; width = 256; }
        else if (i < 24576) { loc = i - 16384; base = a.W1_raw; width = 64; }
        else                { loc = i - 24576; base = a.W2_raw; width = 64; }
        int k2 = loc / width, c = loc % width;
        wp[2 * i]     = __float2half(loadf(base, (2 * k2) * width + c, isb));
        wp[2 * i + 1] = __float2half(loadf(base, (2 * k2 + 1) * width + c, isb));
    } else {
        // bucket scatter (replaces hist + scan + ordered scatter)
        int e = (b - a.cb - a.pb) * 256 + t;
        if (e >= N_E2) return;
        int i64 = flags[0];
        int src, dst;
        if (e < N_EDGES) {
            src = clampn(i64 ? a.edges[2 * e] : a.edges[e]);
            dst = clampn(i64 ? a.edges[2 * (N_EDGES + e)] : a.edges[N_EDGES + e]);
        } else { src = dst = e - N_EDGES; }
        int pos = atomicAdd(&cursor[dst], 1);
        if (pos < BUCKET) csr_src[dst * BUCKET + pos] = src;
    }
}

// ---------------- dispatch 3: degree counting-sort -> perm ----------------
// Blocks of the step kernel take 4 consecutive perm entries; sorting by degree
// makes the 4 waves of a block walk near-equal edge counts (kills the
// max-of-4-Poisson barrier tax). Per-node math is unchanged.
__global__ void degsort_kernel(const int* __restrict__ cursor, int* __restrict__ perm) {
    __shared__ int bins[BUCKET + 1];
    __shared__ int offs[BUCKET + 1];
    const int t = threadIdx.x;
    if (t <= BUCKET) bins[t] = 0;
    __syncthreads();
    for (int n = t; n < N_NODES; n += 256) {
        int d = cursor[n]; d = (d > BUCKET) ? BUCKET : d;
        atomicAdd(&bins[d], 1);
    }
    __syncthreads();
    if (t == 0) {
        int s = 0;
        for (int i = 0; i <= BUCKET; ++i) { offs[i] = s; s += bins[i]; }
    }
    __syncthreads();
    if (t <= BUCKET) bins[t] = 0;     // reuse as per-bin cursors
    __syncthreads();
    for (int n = t; n < N_NODES; n += 256) {
        int d = cursor[n]; d = (d > BUCKET) ? BUCKET : d;
        int p = offs[d] + atomicAdd(&bins[d], 1);
        perm[p] = n;
    }
}

// ---------------- dispatch 4: encoder + proj0 + zero act/final (8 nodes/block) ---
__global__ __launch_bounds__(256) void enc_proj_kernel(
        const float* __restrict__ xf,
        int sX, int sEncW, int sEncB, int sWl, int sBl, int sWr, int sBr,
        __half* __restrict__ xlh, float* __restrict__ xr,
        float* __restrict__ act_tot, float* __restrict__ final_) {
    __shared__ float xs[8][DIM];
    __shared__ float h0[8][DIM];
    const int t = threadIdx.x, pp = t >> 6, d = t & 63;
    const int n0 = blockIdx.x * 8;
    const float* Xf   = xf + sX;
    const float* encW = xf + sEncW;
    const float* encB = xf + sEncB;
    const float* Wl   = xf + sWl;
    const float* bl   = xf + sBl;
    const float* Wr   = xf + sWr;
    const float* br   = xf + sBr;
    ((float*)xs)[t]       = Xf[n0 * DIM + t];
    ((float*)xs)[t + 256] = Xf[n0 * DIM + t + 256];
    final_[(size_t)n0 * DIM + t]       = 0.f;
    final_[(size_t)n0 * DIM + t + 256] = 0.f;
    if (t < 8) act_tot[n0 + t] = 0.f;
    __syncthreads();
    float ah0 = encB[d], ah1 = encB[d];
    for (int k = 0; k < DIM; ++k) {
        float wv = encW[k * DIM + d];
        ah0 += xs[pp][k] * wv;
        ah1 += xs[pp + 4][k] * wv;
    }
    h0[pp][d]     = ah0;
    h0[pp + 4][d] = ah1;
    __syncthreads();
    float al[8] = {0,0,0,0,0,0,0,0}, ar[8] = {0,0,0,0,0,0,0,0};
    for (int k = 0; k < DIM; ++k) {
        float wl = Wl[k * HD + t], wr = Wr[k * HD + t];
        #pragma unroll
        for (int j = 0; j < 8; ++j) { al[j] += h0[j][k] * wl; ar[j] += h0[j][k] * wr; }
    }
    float bbl = bl[t], bbr = br[t];
    #pragma unroll
    for (int j = 0; j < 8; ++j) {
        xlh[(size_t)(n0 + j) * HD + t] = __float2half(al[j] + bbl);
        xr[(size_t)(n0 + j) * HD + t] = ar[j] + bbr;
    }
}

// ---------------- dispatches 5-8: fused step kernel (degree-matched blocks) ------
__global__ __launch_bounds__(256) void step_kernel(
        const __half* __restrict__ xlh_in, const float* __restrict__ xr_in,
        const float* __restrict__ att, const float* __restrict__ gbias,
        const int* __restrict__ cursor, const int* __restrict__ csr_src,
        const int* __restrict__ perm,
        const __half* __restrict__ wp,
        const float* __restrict__ b1, const float* __restrict__ b2,
        const float* __restrict__ actW, const float* __restrict__ actB,
        const float* __restrict__ bl, const float* __restrict__ br,
        float* __restrict__ act_tot, float* __restrict__ final_,
        __half* __restrict__ xlh_out, float* __restrict__ xr_out, int do_proj) {
    __shared__ __align__(16) unsigned int gall_u[4][128];  // 4 nodes x 256 fp16
    __shared__ float part[4][HD];
    __shared__ __half us_h[4][DIM];
    __shared__ float hns[4][DIM];
    __shared__ __half hns_h[4][DIM];
    __shared__ float delta[4];
    const int t = threadIdx.x, w = t >> 6, l = t & 63;
    const int pp = w, d = l;
    const int n0 = blockIdx.x * 4;
    const int n = perm[n0 + w];        // wave w's node (degree-matched within block)

    // ---- Phase 1: edge online-softmax agg (wave per node, bucket CSR) ----
    {
        int deg = cursor[n]; deg = (deg > BUCKET) ? BUCKET : deg;   // >=1 (self-loop)
        const int e0 = n * BUCKET;
        const int e1 = e0 + deg;
        const int elast = e1 - 1;
        const float4 xr4 = ((const float4*)(xr_in + (size_t)n * HD))[l];
        const float4 at4 = ((const float4*)att)[l];
        float m = -1e30f, s = 0.f;
        float4 acc = {0.f, 0.f, 0.f, 0.f};
        uint2 A[4], B[4];
        #pragma unroll
        for (int i = 0; i < 4; ++i) {
            int ee = e0 + i; ee = (ee > elast) ? elast : ee;
            A[i] = ((const uint2*)(xlh_in + (size_t)csr_src[ee] * HD))[l];
        }
        for (int base = e0; base < e1; base += 4) {
            #pragma unroll
            for (int i = 0; i < 4; ++i) {
                int ee = base + 4 + i; ee = (ee > elast) ? elast : ee;
                B[i] = ((const uint2*)(xlh_in + (size_t)csr_src[ee] * HD))[l];
            }
            #pragma unroll
            for (int i = 0; i < 4; ++i) {
                const bool valid = (base + i) < e1;   // wave-uniform
                __half2 h01 = *reinterpret_cast<__half2*>(&A[i].x);
                __half2 h23 = *reinterpret_cast<__half2*>(&A[i].y);
                float2 f01 = __half22float2(h01);
                float2 f23 = __half22float2(h23);
                float c0 = f01.x, c1 = f01.y, c2 = f23.x, c3 = f23.y;
                float z0 = c0 + xr4.x, z1 = c1 + xr4.y, z2 = c2 + xr4.z, z3 = c3 + xr4.w;
                z0 = (z0 > 0.f) ? z0 : 0.2f * z0;
                z1 = (z1 > 0.f) ? z1 : 0.2f * z1;
                z2 = (z2 > 0.f) ? z2 : 0.2f * z2;
                z3 = (z3 > 0.f) ? z3 : 0.2f * z3;
                float p = z0 * at4.x + z1 * at4.y + z2 * at4.z + z3 * at4.w;
                #pragma unroll
                for (int mo = 8; mo; mo >>= 1) p += __shfl_xor(p, mo, 64);
                p = valid ? p : -1e30f;
                float nm = fmaxf(m, p);
                float sc = __expf(m - nm);
                float wv = __expf(p - nm);
                s = s * sc + wv;
                acc.x = acc.x * sc + wv * c0;
                acc.y = acc.y * sc + wv * c1;
                acc.z = acc.z * sc + wv * c2;
                acc.w = acc.w * sc + wv * c3;
                m = nm;
            }
            #pragma unroll
            for (int i = 0; i < 4; ++i) A[i] = B[i];
        }
        const float inv = 1.f / (s + 1e-16f);
        const float4 gb4 = ((const float4*)gbias)[l];
        __half2 o01 = __floats2half2_rn(acc.x * inv + gb4.x, acc.y * inv + gb4.y);
        __half2 o23 = __floats2half2_rn(acc.z * inv + gb4.z, acc.w * inv + gb4.w);
        uint2 outv2;
        outv2.x = *(unsigned int*)&o01;
        outv2.y = *(unsigned int*)&o23;
        ((uint2*)gall_u[w])[l] = outv2;        // g stays in LDS
    }
    __syncthreads();

    // ---- Phase 2: MLP + ACT + proj (4 nodes, dot2, weights shared) ----
    const unsigned int* Wlp = (const unsigned int*)wp;          // [32][256]
    const unsigned int* Wrp = Wlp + 8192;                       // [32][256]
    const unsigned int* W1p = Wlp + 16384;                      // [128][64]
    const unsigned int* W2p = Wlp + 24576;                      // [32][64]

    {
        float acc[4] = {0.f, 0.f, 0.f, 0.f};
        for (int k2 = pp * 32; k2 < pp * 32 + 32; ++k2) {
            unsigned int w2 = W1p[k2 * 64 + d];
            #pragma unroll
            for (int j = 0; j < 4; ++j) acc[j] = dot2(gall_u[j][k2], w2, acc[j]);
        }
        #pragma unroll
        for (int j = 0; j < 4; ++j) part[j][t] = acc[j];
    }
    __syncthreads();
    {
        float v = part[pp][d] + part[pp][64 + d] + part[pp][128 + d] + part[pp][192 + d] + b1[d];
        us_h[pp][d] = __float2half(fmaxf(v, 0.f));
    }
    __syncthreads();
    {
        const unsigned int* us_u = (const unsigned int*)us_h;  // [4][32]
        float acc[4] = {0.f, 0.f, 0.f, 0.f};
        for (int k2 = pp * 8; k2 < pp * 8 + 8; ++k2) {
            unsigned int w2 = W2p[k2 * 64 + d];
            #pragma unroll
            for (int j = 0; j < 4; ++j) acc[j] = dot2(us_u[j * 32 + k2], w2, acc[j]);
        }
        #pragma unroll
        for (int j = 0; j < 4; ++j) part[j][t] = acc[j];
    }
    __syncthreads();
    {
        float hv = part[pp][d] + part[pp][64 + d] + part[pp][128 + d] + part[pp][192 + d] + b2[d];
        hns[pp][d] = hv;
        hns_h[pp][d] = __float2half(hv);
    }
    __syncthreads();
    {
        float p = hns[pp][d] * actW[d];
        #pragma unroll
        for (int mo = 32; mo; mo >>= 1) p += __shfl_xor(p, mo, 64);
        if (d == 0) {
            float term = 1.f / (1.f + __expf(-(p + actB[0])));
            float tot = act_tot[n];
            float nt = fminf(tot + term, 1.f);
            float dl = fminf(term, nt - tot);
            act_tot[n] = tot + dl;
            delta[pp] = dl;
        }
    }
    __syncthreads();
    final_[(size_t)n * DIM + d] += delta[pp] * hns[pp][d];

    if (do_proj) {
        const unsigned int* hn_u = (const unsigned int*)hns_h;  // [4][32]
        float al[4] = {0.f, 0.f, 0.f, 0.f}, ar[4] = {0.f, 0.f, 0.f, 0.f};
        for (int k2 = 0; k2 < 32; ++k2) {
            unsigned int wl2 = Wlp[k2 * 256 + t];
            unsigned int wr2 = Wrp[k2 * 256 + t];
            #pragma unroll
            for (int j = 0; j < 4; ++j) {
                unsigned int hh = hn_u[j * 32 + k2];
                al[j] = dot2(hh, wl2, al[j]);
                ar[j] = dot2(hh, wr2, ar[j]);
            }
        }
        float bbl = bl[t], bbr = br[t];
        #pragma unroll
        for (int j = 0; j < 4; ++j) {
            int nj = perm[n0 + j];
            xlh_out[(size_t)nj * HD + t] = __float2half(al[j] + bbl);
            xr_out[(size_t)nj * HD + t] = ar[j] + bbr;
        }
    }
}

// ---------------- dispatch 9: decoder + log_softmax ----------------
__global__ void decoder_kernel(const float* __restrict__ final_,
                               const float* __restrict__ decW, const float* __restrict__ decB,
                               const int* __restrict__ flags, void* __restrict__ outv) {
    int id = blockIdx.x * 256 + threadIdx.x;
    if (id >= N_NODES * N_PRED * N_CLASS) return;
    int n = id >> 5, r = id & 31, p = r >> 4, c = r & 15;
    float acc = decB[p * N_CLASS + c];
    for (int dd = 0; dd < DIM; ++dd)
        acc += final_[(size_t)n * DIM + dd] * decW[(p * DIM + dd) * N_CLASS + c];
    float mx = acc;
    #pragma unroll
    for (int mo = 8; mo; mo >>= 1) mx = fmaxf(mx, __shfl_xor(mx, mo, 64));
    float ex = __expf(acc - mx);
    float ss = ex;
    #pragma unroll
    for (int mo = 8; mo; mo >>= 1) ss += __shfl_xor(ss, mo, 64);
    float ov = acc - mx - logf(ss);
    int oi = p * (N_NODES * N_CLASS) + n * N_CLASS + c;
    if (flags[1]) ((bf16*)outv)[oi] = __float2bfloat16(ov);
    else          ((float*)outv)[oi] = ov;
}

// ---------------- host launcher ----------------
static size_t align256(size_t x) { return (x + 255) & ~size_t(255); }

extern "C" void kernel_launch(void* const* d_in, const int* in_sizes, int n_in,
                              void* d_out, int out_size, void* d_ws, size_t ws_size,
                              hipStream_t stream) {
    const int* edges = (const int*)d_in[1];

    static const int fids[17] = {0, 2, 3, 4, 5, 6, 7, 8, 9, 10, 11, 12, 13, 14, 15, 16, 17};
    ConvTable tab;
    int cum = 0;
    for (int i = 0; i < 17; ++i) {
        tab.src[i] = d_in[fids[i]];
        tab.start[i] = cum;
        cum += in_sizes[fids[i]];
    }
    tab.start[17] = cum;

    // workspace carve-up (~39 MB)
    char* w = (char*)d_ws;
    size_t o = 0;
    int* flags     = (int*)(w + o); o = align256(o + 16 * sizeof(int));
    int* cursor    = (int*)(w + o); o = align256(o + N_NODES * sizeof(int));
    float* act_tot = (float*)(w + o); o = align256(o + N_NODES * sizeof(float));
    float* final_  = (float*)(w + o); o = align256(o + (size_t)N_NODES * DIM * sizeof(float));
    int* csr_src   = (int*)(w + o); o = align256(o + (size_t)N_NODES * BUCKET * sizeof(int));
    int* perm      = (int*)(w + o); o = align256(o + N_NODES * sizeof(int));
    float* xf      = (float*)(w + o); o = align256(o + (size_t)cum * sizeof(float));
    __half* xlh_a  = (__half*)(w + o); o = align256(o + (size_t)N_NODES * HD * sizeof(__half));
    float* xr_a    = (float*)(w + o); o = align256(o + (size_t)N_NODES * HD * sizeof(float));
    __half* xlh_b  = (__half*)(w + o); o = align256(o + (size_t)N_NODES * HD * sizeof(__half));
    float* xr_b    = (float*)(w + o); o = align256(o + (size_t)N_NODES * HD * sizeof(float));
    __half* wpack  = (__half*)(w + o); o = align256(o + 53248 * sizeof(__half));
    if (o > ws_size) return;  // diagnostic: zero output => ws too small

    const float* att  = xf + tab.start[7];
    const float* gbias= xf + tab.start[8];
    const float* b1   = xf + tab.start[10];
    const float* b2   = xf + tab.start[12];
    const float* actW = xf + tab.start[13];
    const float* actB = xf + tab.start[14];
    const float* decW = xf + tab.start[15];
    const float* decB = xf + tab.start[16];

    // 1: detect + zero cursor
    detect_kernel<<<(N_NODES + 255) / 256, 256, 0, stream>>>(
        (const unsigned int*)d_in[1], (const unsigned short*)d_in[0], flags, cursor);

    // 2: convert || pack || bucket-scatter
    PreArgs pa;
    pa.tab = tab;
    pa.Wl_raw = d_in[4]; pa.Wr_raw = d_in[6]; pa.W1_raw = d_in[10]; pa.W2_raw = d_in[12];
    pa.edges = edges;
    pa.cb = (cum + 255) / 256;
    pa.pb = (26624 + 255) / 256;
    int sb = (N_E2 + 255) / 256;
    pre_kernel<<<pa.cb + pa.pb + sb, 256, 0, stream>>>(pa, flags, xf, wpack, cursor, csr_src);

    // 3: degree counting-sort -> perm
    degsort_kernel<<<1, 256, 0, stream>>>(cursor, perm);

    // 4: encoder + proj0 (+zero act/final)
    enc_proj_kernel<<<N_NODES / 8, 256, 0, stream>>>(
        xf, tab.start[0], tab.start[1], tab.start[2],
        tab.start[3], tab.start[4], tab.start[5], tab.start[6],
        xlh_a, xr_a, act_tot, final_);

    // 5-8: fused universal-transformer steps
    __half* xl_in = xlh_a;  float* xr_in = xr_a;
    __half* xl_out = xlh_b; float* xr_out = xr_b;
    for (int step = 0; step < N_STEPS; ++step) {
        step_kernel<<<N_NODES / 4, 256, 0, stream>>>(
            xl_in, xr_in, att, gbias, cursor, csr_src, perm, wpack,
            b1, b2, actW, actB,
            xf + tab.start[4], xf + tab.start[6],
            act_tot, final_, xl_out, xr_out, (step < N_STEPS - 1) ? 1 : 0);
        __half* th = xl_in; xl_in = xl_out; xl_out = th;
        float* tf = xr_in; xr_in = xr_out; xr_out = tf;
    }

    // 9: decoder
    int db = (N_NODES * N_PRED * N_CLASS + 255) / 256;
    decoder_kernel<<<db, 256, 0, stream>>>(final_, decW, decB, flags, d_out);
}

// Round 16
// 300.913 us; speedup vs baseline: 1.0481x; 1.0481x over previous
//
#include <hip/hip_runtime.h>
#include <hip/hip_bf16.h>
#include <hip/hip_fp16.h>

#define N_NODES 10000
#define N_EDGES 160000
#define N_E2    (N_EDGES + N_NODES)   // with self-loops
#define DIM     64
#define HD      256                    // HEADS * DIM
#define N_PRED  2
#define N_CLASS 16
#define N_STEPS 4
#define BUCKET  64                     // fixed CSR bucket per node; P(deg>64) ~ 1e-16

typedef __hip_bfloat16 bf16;
__device__ __forceinline__ float b2f(bf16 v) { return __bfloat162float(v); }
__device__ __forceinline__ int clampn(int v) { return v < 0 ? 0 : (v >= N_NODES ? N_NODES - 1 : v); }

typedef _Float16 h2_t __attribute__((ext_vector_type(2)));

// fp16 pair dot with fp32 accumulate (v_dot2_f32_f16)
__device__ __forceinline__ float dot2(unsigned int a, unsigned int b, float c) {
#if __has_builtin(__builtin_amdgcn_fdot2)
    h2_t av, bv;
    __builtin_memcpy(&av, &a, 4);
    __builtin_memcpy(&bv, &b, 4);
    return __builtin_amdgcn_fdot2(av, bv, c, false);
#else
    __half2 ah = *(__half2*)&a, bh = *(__half2*)&b;
    float2 af = __half22float2(ah), bf = __half22float2(bh);
    return c + af.x * bf.x + af.y * bf.y;
#endif
}

struct ConvTable {
    const void* src[17];
    int start[18];
};

__device__ __forceinline__ float loadf(const void* p, int idx, int isbf16) {
    return isbf16 ? b2f(((const bf16*)p)[idx]) : ((const float*)p)[idx];
}

// ---------------- dispatch 1: dtype detection + zero cursor ----------------
__global__ void detect_kernel(const unsigned int* __restrict__ e32,
                              const unsigned short* __restrict__ x16,
                              int* __restrict__ flags, int* __restrict__ cursor) {
    int i = blockIdx.x * 256 + threadIdx.x;
    if (i < N_NODES) cursor[i] = 0;
    if (blockIdx.x != 0) return;
    __shared__ int ce, cf;
    if (threadIdx.x == 0) { ce = 0; cf = 0; }
    __syncthreads();
    int le = 0;
    for (int k = threadIdx.x; k < 2048; k += 256)
        le += (e32[2 * k + 1] != 0u) ? 1 : 0;
    int lf = 0;
    for (int k = threadIdx.x; k < 1024; k += 256) {
        unsigned short u = x16[2 * k];
        int ex = (u >> 7) & 0xFF;
        lf += (u == 0 || (ex >= 114 && ex <= 141)) ? 1 : 0;
    }
    atomicAdd(&ce, le);
    atomicAdd(&cf, lf);
    __syncthreads();
    if (threadIdx.x == 0) {
        flags[0] = (ce < 1024) ? 1 : 0;   // edge_index is int64
        flags[1] = (cf >= 512) ? 1 : 0;   // floats are bf16
    }
}

// ---------------- dispatch 2: convert || pack || bucket-scatter ----------------
struct PreArgs {
    ConvTable tab;
    const void* Wl_raw; const void* Wr_raw; const void* W1_raw; const void* W2_raw;
    const int* edges;
    int cb, pb;          // block counts: convert, pack
};

__global__ void pre_kernel(PreArgs a, const int* __restrict__ flags,
                           float* __restrict__ xf, __half* __restrict__ wp,
                           int* __restrict__ cursor, int* __restrict__ csr_src) {
    const int b = blockIdx.x, t = threadIdx.x;
    const int isb = flags[1];
    if (b < a.cb) {
        int i = b * 256 + t;
        if (i >= a.tab.start[17]) return;
        int j = 0;
        #pragma unroll
        for (int k = 1; k < 17; ++k) j += (i >= a.tab.start[k]) ? 1 : 0;
        xf[i] = loadf(a.tab.src[j], i - a.tab.start[j], isb);
    } else if (b < a.cb + a.pb) {
        int i = (b - a.cb) * 256 + t;
        if (i >= 26624) return;
        const void* base; int width, loc;
        if (i < 8192)       { loc = i;         base = a.Wl_raw; width = 256; }
        else if (i < 16384) { loc = i - 8192;  base = a.Wr_raw; width = 256; }
        else if (i < 24576) { loc = i - 16384; base = a.W1_raw; width = 64; }
        else                { loc = i - 24576; base = a.W2_raw; width = 64; }
        int k2 = loc / width, c = loc % width;
        wp[2 * i]     = __float2half(loadf(base, (2 * k2) * width + c, isb));
        wp[2 * i + 1] = __float2half(loadf(base, (2 * k2 + 1) * width + c, isb));
    } else {
        // bucket scatter (replaces hist + scan + ordered scatter)
        int e = (b - a.cb - a.pb) * 256 + t;
        if (e >= N_E2) return;
        int i64 = flags[0];
        int src, dst;
        if (e < N_EDGES) {
            src = clampn(i64 ? a.edges[2 * e] : a.edges[e]);
            dst = clampn(i64 ? a.edges[2 * (N_EDGES + e)] : a.edges[N_EDGES + e]);
        } else { src = dst = e - N_EDGES; }
        int pos = atomicAdd(&cursor[dst], 1);
        if (pos < BUCKET) csr_src[dst * BUCKET + pos] = src;
    }
}

// ---------------- dispatch 3: encoder + proj0 + zero act/final (8 nodes/block) ---
__global__ __launch_bounds__(256) void enc_proj_kernel(
        const float* __restrict__ xf,
        int sX, int sEncW, int sEncB, int sWl, int sBl, int sWr, int sBr,
        __half* __restrict__ xlh, __half* __restrict__ xrh,
        float* __restrict__ act_tot, float* __restrict__ final_) {
    __shared__ float xs[8][DIM];
    __shared__ float h0[8][DIM];
    const int t = threadIdx.x, pp = t >> 6, d = t & 63;
    const int n0 = blockIdx.x * 8;
    const float* Xf   = xf + sX;
    const float* encW = xf + sEncW;
    const float* encB = xf + sEncB;
    const float* Wl   = xf + sWl;
    const float* bl   = xf + sBl;
    const float* Wr   = xf + sWr;
    const float* br   = xf + sBr;
    ((float*)xs)[t]       = Xf[n0 * DIM + t];
    ((float*)xs)[t + 256] = Xf[n0 * DIM + t + 256];
    final_[(size_t)n0 * DIM + t]       = 0.f;
    final_[(size_t)n0 * DIM + t + 256] = 0.f;
    if (t < 8) act_tot[n0 + t] = 0.f;
    __syncthreads();
    float ah0 = encB[d], ah1 = encB[d];
    for (int k = 0; k < DIM; ++k) {
        float wv = encW[k * DIM + d];
        ah0 += xs[pp][k] * wv;
        ah1 += xs[pp + 4][k] * wv;
    }
    h0[pp][d]     = ah0;
    h0[pp + 4][d] = ah1;
    __syncthreads();
    float al[8] = {0,0,0,0,0,0,0,0}, ar[8] = {0,0,0,0,0,0,0,0};
    for (int k = 0; k < DIM; ++k) {
        float wl = Wl[k * HD + t], wr = Wr[k * HD + t];
        #pragma unroll
        for (int j = 0; j < 8; ++j) { al[j] += h0[j][k] * wl; ar[j] += h0[j][k] * wr; }
    }
    float bbl = bl[t], bbr = br[t];
    #pragma unroll
    for (int j = 0; j < 8; ++j) {
        xlh[(size_t)(n0 + j) * HD + t] = __float2half(al[j] + bbl);
        xrh[(size_t)(n0 + j) * HD + t] = __float2half(ar[j] + bbr);
    }
}

// ---------------- dispatches 4-7: fused step kernel ----------------
// Phase 1: wave w = node n0+w, online-softmax edge walk over the node's bucket
// with 4+4 double-buffered gathers; g -> LDS. Phase 2: block-wide MLP + ACT +
// next-step proj (weights shared across the block's 4 nodes). min 8 waves/EU
// requested via launch_bounds (VGPR 56 fits the 64 cap).
__global__ __launch_bounds__(256, 8) void step_kernel(
        const __half* __restrict__ xlh_in, const __half* __restrict__ xrh_in,
        const float* __restrict__ att, const float* __restrict__ gbias,
        const int* __restrict__ cursor, const int* __restrict__ csr_src,
        const __half* __restrict__ wp,
        const float* __restrict__ b1, const float* __restrict__ b2,
        const float* __restrict__ actW, const float* __restrict__ actB,
        const float* __restrict__ bl, const float* __restrict__ br,
        float* __restrict__ act_tot, float* __restrict__ final_,
        __half* __restrict__ xlh_out, __half* __restrict__ xrh_out, int do_proj) {
    __shared__ __align__(16) unsigned int gall_u[4][128];  // 4 nodes x 256 fp16
    __shared__ float part[4][HD];
    __shared__ __half us_h[4][DIM];
    __shared__ float hns[4][DIM];
    __shared__ __half hns_h[4][DIM];
    __shared__ float delta[4];
    const int t = threadIdx.x, w = t >> 6, l = t & 63;
    const int pp = w, d = l;
    const int n0 = blockIdx.x * 4;
    const int n = n0 + w;

    // ---- Phase 1: edge online-softmax agg (wave per node, bucket CSR) ----
    {
        int deg = cursor[n]; deg = (deg > BUCKET) ? BUCKET : deg;   // >=1 (self-loop)
        const int e0 = n * BUCKET;
        const int e1 = e0 + deg;
        const int elast = e1 - 1;
        float4 xr4;
        {
            uint2 xru = ((const uint2*)(xrh_in + (size_t)n * HD))[l];
            float2 f01 = __half22float2(*reinterpret_cast<__half2*>(&xru.x));
            float2 f23 = __half22float2(*reinterpret_cast<__half2*>(&xru.y));
            xr4.x = f01.x; xr4.y = f01.y; xr4.z = f23.x; xr4.w = f23.y;
        }
        const float4 at4 = ((const float4*)att)[l];
        float m = -1e30f, s = 0.f;
        float4 acc = {0.f, 0.f, 0.f, 0.f};
        uint2 A[4], B[4];
        #pragma unroll
        for (int i = 0; i < 4; ++i) {
            int ee = e0 + i; ee = (ee > elast) ? elast : ee;
            A[i] = ((const uint2*)(xlh_in + (size_t)csr_src[ee] * HD))[l];
        }
        for (int base = e0; base < e1; base += 4) {
            #pragma unroll
            for (int i = 0; i < 4; ++i) {
                int ee = base + 4 + i; ee = (ee > elast) ? elast : ee;
                B[i] = ((const uint2*)(xlh_in + (size_t)csr_src[ee] * HD))[l];
            }
            #pragma unroll
            for (int i = 0; i < 4; ++i) {
                const bool valid = (base + i) < e1;   // wave-uniform
                __half2 h01 = *reinterpret_cast<__half2*>(&A[i].x);
                __half2 h23 = *reinterpret_cast<__half2*>(&A[i].y);
                float2 f01 = __half22float2(h01);
                float2 f23 = __half22float2(h23);
                float c0 = f01.x, c1 = f01.y, c2 = f23.x, c3 = f23.y;
                float z0 = c0 + xr4.x, z1 = c1 + xr4.y, z2 = c2 + xr4.z, z3 = c3 + xr4.w;
                z0 = (z0 > 0.f) ? z0 : 0.2f * z0;
                z1 = (z1 > 0.f) ? z1 : 0.2f * z1;
                z2 = (z2 > 0.f) ? z2 : 0.2f * z2;
                z3 = (z3 > 0.f) ? z3 : 0.2f * z3;
                float p = z0 * at4.x + z1 * at4.y + z2 * at4.z + z3 * at4.w;
                #pragma unroll
                for (int mo = 8; mo; mo >>= 1) p += __shfl_xor(p, mo, 64);
                p = valid ? p : -1e30f;
                float nm = fmaxf(m, p);
                float sc = __expf(m - nm);
                float wv = __expf(p - nm);
                s = s * sc + wv;
                acc.x = acc.x * sc + wv * c0;
                acc.y = acc.y * sc + wv * c1;
                acc.z = acc.z * sc + wv * c2;
                acc.w = acc.w * sc + wv * c3;
                m = nm;
            }
            #pragma unroll
            for (int i = 0; i < 4; ++i) A[i] = B[i];
        }
        const float inv = 1.f / (s + 1e-16f);
        const float4 gb4 = ((const float4*)gbias)[l];
        __half2 o01 = __floats2half2_rn(acc.x * inv + gb4.x, acc.y * inv + gb4.y);
        __half2 o23 = __floats2half2_rn(acc.z * inv + gb4.z, acc.w * inv + gb4.w);
        uint2 outv2;
        outv2.x = *(unsigned int*)&o01;
        outv2.y = *(unsigned int*)&o23;
        ((uint2*)gall_u[w])[l] = outv2;        // g stays in LDS
    }
    __syncthreads();

    // ---- Phase 2: MLP + ACT + proj (4 nodes, dot2, weights shared) ----
    const unsigned int* Wlp = (const unsigned int*)wp;          // [32][256]
    const unsigned int* Wrp = Wlp + 8192;                       // [32][256]
    const unsigned int* W1p = Wlp + 16384;                      // [128][64]
    const unsigned int* W2p = Wlp + 24576;                      // [32][64]

    {
        float acc[4] = {0.f, 0.f, 0.f, 0.f};
        for (int k2 = pp * 32; k2 < pp * 32 + 32; ++k2) {
            unsigned int w2 = W1p[k2 * 64 + d];
            #pragma unroll
            for (int j = 0; j < 4; ++j) acc[j] = dot2(gall_u[j][k2], w2, acc[j]);
        }
        #pragma unroll
        for (int j = 0; j < 4; ++j) part[j][t] = acc[j];
    }
    __syncthreads();
    {
        float v = part[pp][d] + part[pp][64 + d] + part[pp][128 + d] + part[pp][192 + d] + b1[d];
        us_h[pp][d] = __float2half(fmaxf(v, 0.f));
    }
    __syncthreads();
    {
        const unsigned int* us_u = (const unsigned int*)us_h;  // [4][32]
        float acc[4] = {0.f, 0.f, 0.f, 0.f};
        for (int k2 = pp * 8; k2 < pp * 8 + 8; ++k2) {
            unsigned int w2 = W2p[k2 * 64 + d];
            #pragma unroll
            for (int j = 0; j < 4; ++j) acc[j] = dot2(us_u[j * 32 + k2], w2, acc[j]);
        }
        #pragma unroll
        for (int j = 0; j < 4; ++j) part[j][t] = acc[j];
    }
    __syncthreads();
    {
        float hv = part[pp][d] + part[pp][64 + d] + part[pp][128 + d] + part[pp][192 + d] + b2[d];
        hns[pp][d] = hv;
        hns_h[pp][d] = __float2half(hv);
    }
    __syncthreads();
    {
        float p = hns[pp][d] * actW[d];
        #pragma unroll
        for (int mo = 32; mo; mo >>= 1) p += __shfl_xor(p, mo, 64);
        if (d == 0) {
            float term = 1.f / (1.f + __expf(-(p + actB[0])));
            float tot = act_tot[n0 + pp];
            float nt = fminf(tot + term, 1.f);
            float dl = fminf(term, nt - tot);
            act_tot[n0 + pp] = tot + dl;
            delta[pp] = dl;
        }
    }
    __syncthreads();
    final_[(size_t)(n0 + pp) * DIM + d] += delta[pp] * hns[pp][d];

    if (do_proj) {
        const unsigned int* hn_u = (const unsigned int*)hns_h;  // [4][32]
        float al[4] = {0.f, 0.f, 0.f, 0.f}, ar[4] = {0.f, 0.f, 0.f, 0.f};
        for (int k2 = 0; k2 < 32; ++k2) {
            unsigned int wl2 = Wlp[k2 * 256 + t];
            unsigned int wr2 = Wrp[k2 * 256 + t];
            #pragma unroll
            for (int j = 0; j < 4; ++j) {
                unsigned int hh = hn_u[j * 32 + k2];
                al[j] = dot2(hh, wl2, al[j]);
                ar[j] = dot2(hh, wr2, ar[j]);
            }
        }
        float bbl = bl[t], bbr = br[t];
        #pragma unroll
        for (int j = 0; j < 4; ++j) {
            xlh_out[(size_t)(n0 + j) * HD + t] = __float2half(al[j] + bbl);
            xrh_out[(size_t)(n0 + j) * HD + t] = __float2half(ar[j] + bbr);
        }
    }
}

// ---------------- dispatch 8: decoder + log_softmax ----------------
__global__ void decoder_kernel(const float* __restrict__ final_,
                               const float* __restrict__ decW, const float* __restrict__ decB,
                               const int* __restrict__ flags, void* __restrict__ outv) {
    int id = blockIdx.x * 256 + threadIdx.x;
    if (id >= N_NODES * N_PRED * N_CLASS) return;
    int n = id >> 5, r = id & 31, p = r >> 4, c = r & 15;
    float acc = decB[p * N_CLASS + c];
    for (int dd = 0; dd < DIM; ++dd)
        acc += final_[(size_t)n * DIM + dd] * decW[(p * DIM + dd) * N_CLASS + c];
    float mx = acc;
    #pragma unroll
    for (int mo = 8; mo; mo >>= 1) mx = fmaxf(mx, __shfl_xor(mx, mo, 64));
    float ex = __expf(acc - mx);
    float ss = ex;
    #pragma unroll
    for (int mo = 8; mo; mo >>= 1) ss += __shfl_xor(ss, mo, 64);
    float ov = acc - mx - logf(ss);
    int oi = p * (N_NODES * N_CLASS) + n * N_CLASS + c;
    if (flags[1]) ((bf16*)outv)[oi] = __float2bfloat16(ov);
    else          ((float*)outv)[oi] = ov;
}

// ---------------- host launcher ----------------
static size_t align256(size_t x) { return (x + 255) & ~size_t(255); }

extern "C" void kernel_launch(void* const* d_in, const int* in_sizes, int n_in,
                              void* d_out, int out_size, void* d_ws, size_t ws_size,
                              hipStream_t stream) {
    const int* edges = (const int*)d_in[1];

    static const int fids[17] = {0, 2, 3, 4, 5, 6, 7, 8, 9, 10, 11, 12, 13, 14, 15, 16, 17};
    ConvTable tab;
    int cum = 0;
    for (int i = 0; i < 17; ++i) {
        tab.src[i] = d_in[fids[i]];
        tab.start[i] = cum;
        cum += in_sizes[fids[i]];
    }
    tab.start[17] = cum;

    // workspace carve-up (~34 MB)
    char* w = (char*)d_ws;
    size_t o = 0;
    int* flags     = (int*)(w + o); o = align256(o + 16 * sizeof(int));
    int* cursor    = (int*)(w + o); o = align256(o + N_NODES * sizeof(int));
    float* act_tot = (float*)(w + o); o = align256(o + N_NODES * sizeof(float));
    float* final_  = (float*)(w + o); o = align256(o + (size_t)N_NODES * DIM * sizeof(float));
    int* csr_src   = (int*)(w + o); o = align256(o + (size_t)N_NODES * BUCKET * sizeof(int));
    float* xf      = (float*)(w + o); o = align256(o + (size_t)cum * sizeof(float));
    __half* xlh_a  = (__half*)(w + o); o = align256(o + (size_t)N_NODES * HD * sizeof(__half));
    __half* xrh_a  = (__half*)(w + o); o = align256(o + (size_t)N_NODES * HD * sizeof(__half));
    __half* xlh_b  = (__half*)(w + o); o = align256(o + (size_t)N_NODES * HD * sizeof(__half));
    __half* xrh_b  = (__half*)(w + o); o = align256(o + (size_t)N_NODES * HD * sizeof(__half));
    __half* wpack  = (__half*)(w + o); o = align256(o + 53248 * sizeof(__half));
    if (o > ws_size) return;  // diagnostic: zero output => ws too small

    const float* att  = xf + tab.start[7];
    const float* gbias= xf + tab.start[8];
    const float* b1   = xf + tab.start[10];
    const float* b2   = xf + tab.start[12];
    const float* actW = xf + tab.start[13];
    const float* actB = xf + tab.start[14];
    const float* decW = xf + tab.start[15];
    const float* decB = xf + tab.start[16];

    // 1: detect + zero cursor
    detect_kernel<<<(N_NODES + 255) / 256, 256, 0, stream>>>(
        (const unsigned int*)d_in[1], (const unsigned short*)d_in[0], flags, cursor);

    // 2: convert || pack || bucket-scatter
    PreArgs pa;
    pa.tab = tab;
    pa.Wl_raw = d_in[4]; pa.Wr_raw = d_in[6]; pa.W1_raw = d_in[10]; pa.W2_raw = d_in[12];
    pa.edges = edges;
    pa.cb = (cum + 255) / 256;
    pa.pb = (26624 + 255) / 256;
    int sb = (N_E2 + 255) / 256;
    pre_kernel<<<pa.cb + pa.pb + sb, 256, 0, stream>>>(pa, flags, xf, wpack, cursor, csr_src);

    // 3: encoder + proj0 (+zero act/final)
    enc_proj_kernel<<<N_NODES / 8, 256, 0, stream>>>(
        xf, tab.start[0], tab.start[1], tab.start[2],
        tab.start[3], tab.start[4], tab.start[5], tab.start[6],
        xlh_a, xrh_a, act_tot, final_);

    // 4-7: fused universal-transformer steps
    __half* xl_in = xlh_a;  __half* xr_in = xrh_a;
    __half* xl_out = xlh_b; __half* xr_out = xrh_b;
    for (int step = 0; step < N_STEPS; ++step) {
        step_kernel<<<N_NODES / 4, 256, 0, stream>>>(
            xl_in, xr_in, att, gbias, cursor, csr_src, wpack,
            b1, b2, actW, actB,
            xf + tab.start[4], xf + tab.start[6],
            act_tot, final_, xl_out, xr_out, (step < N_STEPS - 1) ? 1 : 0);
        __half* th = xl_in; xl_in = xl_out; xl_out = th;
        __half* tf = xr_in; xr_in = xr_out; xr_out = tf;
    }

    // 8: decoder
    int db = (N_NODES * N_PRED * N_CLASS + 255) / 256;
    decoder_kernel<<<db, 256, 0, stream>>>(final_, decW, decB, flags, d_out);
}

// Round 17
// 281.643 us; speedup vs baseline: 1.1199x; 1.0684x over previous
//
#include <hip/hip_runtime.h>
#include <hip/hip_bf16.h>
#include <hip/hip_fp16.h>

#define N_NODES 10000
#define N_EDGES 160000
#define N_E2    (N_EDGES + N_NODES)   // with self-loops
#define DIM     64
#define HD      256                    // HEADS * DIM
#define N_PRED  2
#define N_CLASS 16
#define N_STEPS 4
#define BUCKET  64                     // fixed CSR bucket per node; P(deg>64) ~ 1e-16

typedef __hip_bfloat16 bf16;
__device__ __forceinline__ float b2f(bf16 v) { return __bfloat162float(v); }
__device__ __forceinline__ int clampn(int v) { return v < 0 ? 0 : (v >= N_NODES ? N_NODES - 1 : v); }

typedef _Float16 h2_t __attribute__((ext_vector_type(2)));

// fp16 pair dot with fp32 accumulate (v_dot2_f32_f16)
__device__ __forceinline__ float dot2(unsigned int a, unsigned int b, float c) {
#if __has_builtin(__builtin_amdgcn_fdot2)
    h2_t av, bv;
    __builtin_memcpy(&av, &a, 4);
    __builtin_memcpy(&bv, &b, 4);
    return __builtin_amdgcn_fdot2(av, bv, c, false);
#else
    __half2 ah = *(__half2*)&a, bh = *(__half2*)&b;
    float2 af = __half22float2(ah), bf = __half22float2(bh);
    return c + af.x * bf.x + af.y * bf.y;
#endif
}

struct ConvTable {
    const void* src[17];
    int start[18];
};

__device__ __forceinline__ float loadf(const void* p, int idx, int isbf16) {
    return isbf16 ? b2f(((const bf16*)p)[idx]) : ((const float*)p)[idx];
}

// ---------------- dispatch 1: dtype detection + zero cursor ----------------
__global__ void detect_kernel(const unsigned int* __restrict__ e32,
                              const unsigned short* __restrict__ x16,
                              int* __restrict__ flags, int* __restrict__ cursor) {
    int i = blockIdx.x * 256 + threadIdx.x;
    if (i < N_NODES) cursor[i] = 0;
    if (blockIdx.x != 0) return;
    __shared__ int ce, cf;
    if (threadIdx.x == 0) { ce = 0; cf = 0; }
    __syncthreads();
    int le = 0;
    for (int k = threadIdx.x; k < 2048; k += 256)
        le += (e32[2 * k + 1] != 0u) ? 1 : 0;
    int lf = 0;
    for (int k = threadIdx.x; k < 1024; k += 256) {
        unsigned short u = x16[2 * k];
        int ex = (u >> 7) & 0xFF;
        lf += (u == 0 || (ex >= 114 && ex <= 141)) ? 1 : 0;
    }
    atomicAdd(&ce, le);
    atomicAdd(&cf, lf);
    __syncthreads();
    if (threadIdx.x == 0) {
        flags[0] = (ce < 1024) ? 1 : 0;   // edge_index is int64
        flags[1] = (cf >= 512) ? 1 : 0;   // floats are bf16
    }
}

// ---------------- dispatch 2: convert || pack || bucket-scatter ----------------
struct PreArgs {
    ConvTable tab;
    const void* Wl_raw; const void* Wr_raw; const void* W1_raw; const void* W2_raw;
    const int* edges;
    int cb, pb;          // block counts: convert, pack
};

__global__ void pre_kernel(PreArgs a, const int* __restrict__ flags,
                           float* __restrict__ xf, __half* __restrict__ wp,
                           int* __restrict__ cursor, int* __restrict__ csr_src) {
    const int b = blockIdx.x, t = threadIdx.x;
    const int isb = flags[1];
    if (b < a.cb) {
        int i = b * 256 + t;
        if (i >= a.tab.start[17]) return;
        int j = 0;
        #pragma unroll
        for (int k = 1; k < 17; ++k) j += (i >= a.tab.start[k]) ? 1 : 0;
        xf[i] = loadf(a.tab.src[j], i - a.tab.start[j], isb);
    } else if (b < a.cb + a.pb) {
        int i = (b - a.cb) * 256 + t;
        if (i >= 26624) return;
        const void* base; int width, loc;
        if (i < 8192)       { loc = i;         base = a.Wl_raw; width = 256; }
        else if (i < 16384) { loc = i - 8192;  base = a.Wr_raw; width = 256; }
        else if (i < 24576) { loc = i - 16384; base = a.W1_raw; width = 64; }
        else                { loc = i - 24576; base = a.W2_raw; width = 64; }
        int k2 = loc / width, c = loc % width;
        wp[2 * i]     = __float2half(loadf(base, (2 * k2) * width + c, isb));
        wp[2 * i + 1] = __float2half(loadf(base, (2 * k2 + 1) * width + c, isb));
    } else {
        // bucket scatter (replaces hist + scan + ordered scatter)
        int e = (b - a.cb - a.pb) * 256 + t;
        if (e >= N_E2) return;
        int i64 = flags[0];
        int src, dst;
        if (e < N_EDGES) {
            src = clampn(i64 ? a.edges[2 * e] : a.edges[e]);
            dst = clampn(i64 ? a.edges[2 * (N_EDGES + e)] : a.edges[N_EDGES + e]);
        } else { src = dst = e - N_EDGES; }
        int pos = atomicAdd(&cursor[dst], 1);
        if (pos < BUCKET) csr_src[dst * BUCKET + pos] = src;
    }
}

// ---------------- dispatch 3: encoder + proj0 + zero act/final (8 nodes/block) ---
__global__ __launch_bounds__(256) void enc_proj_kernel(
        const float* __restrict__ xf,
        int sX, int sEncW, int sEncB, int sWl, int sBl, int sWr, int sBr,
        __half* __restrict__ xlh, __half* __restrict__ xrh,
        float* __restrict__ act_tot, float* __restrict__ final_) {
    __shared__ float xs[8][DIM];
    __shared__ float h0[8][DIM];
    const int t = threadIdx.x, pp = t >> 6, d = t & 63;
    const int n0 = blockIdx.x * 8;
    const float* Xf   = xf + sX;
    const float* encW = xf + sEncW;
    const float* encB = xf + sEncB;
    const float* Wl   = xf + sWl;
    const float* bl   = xf + sBl;
    const float* Wr   = xf + sWr;
    const float* br   = xf + sBr;
    ((float*)xs)[t]       = Xf[n0 * DIM + t];
    ((float*)xs)[t + 256] = Xf[n0 * DIM + t + 256];
    final_[(size_t)n0 * DIM + t]       = 0.f;
    final_[(size_t)n0 * DIM + t + 256] = 0.f;
    if (t < 8) act_tot[n0 + t] = 0.f;
    __syncthreads();
    float ah0 = encB[d], ah1 = encB[d];
    for (int k = 0; k < DIM; ++k) {
        float wv = encW[k * DIM + d];
        ah0 += xs[pp][k] * wv;
        ah1 += xs[pp + 4][k] * wv;
    }
    h0[pp][d]     = ah0;
    h0[pp + 4][d] = ah1;
    __syncthreads();
    float al[8] = {0,0,0,0,0,0,0,0}, ar[8] = {0,0,0,0,0,0,0,0};
    for (int k = 0; k < DIM; ++k) {
        float wl = Wl[k * HD + t], wr = Wr[k * HD + t];
        #pragma unroll
        for (int j = 0; j < 8; ++j) { al[j] += h0[j][k] * wl; ar[j] += h0[j][k] * wr; }
    }
    float bbl = bl[t], bbr = br[t];
    #pragma unroll
    for (int j = 0; j < 8; ++j) {
        xlh[(size_t)(n0 + j) * HD + t] = __float2half(al[j] + bbl);
        xrh[(size_t)(n0 + j) * HD + t] = __float2half(ar[j] + bbr);
    }
}

// ---------------- dispatches 4-7: fused step kernel ----------------
// Phase 1: wave w = node n0+w, online-softmax edge walk over the node's bucket
// with 4+4 double-buffered gathers; g -> LDS. Phase 2: block-wide MLP + ACT +
// next-step proj (weights shared across the block's 4 nodes).
// NOTE: no min-waves launch_bounds — r16 showed (256,8) forces VGPR 56->32 and
// spills (WRITE_SIZE 17.6->40 MB, step +3 µs). Natural VGPR ~56 is optimal.
__global__ __launch_bounds__(256) void step_kernel(
        const __half* __restrict__ xlh_in, const __half* __restrict__ xrh_in,
        const float* __restrict__ att, const float* __restrict__ gbias,
        const int* __restrict__ cursor, const int* __restrict__ csr_src,
        const __half* __restrict__ wp,
        const float* __restrict__ b1, const float* __restrict__ b2,
        const float* __restrict__ actW, const float* __restrict__ actB,
        const float* __restrict__ bl, const float* __restrict__ br,
        float* __restrict__ act_tot, float* __restrict__ final_,
        __half* __restrict__ xlh_out, __half* __restrict__ xrh_out, int do_proj) {
    __shared__ __align__(16) unsigned int gall_u[4][128];  // 4 nodes x 256 fp16
    __shared__ float part[4][HD];
    __shared__ __half us_h[4][DIM];
    __shared__ float hns[4][DIM];
    __shared__ __half hns_h[4][DIM];
    __shared__ float delta[4];
    const int t = threadIdx.x, w = t >> 6, l = t & 63;
    const int pp = w, d = l;
    const int n0 = blockIdx.x * 4;
    const int n = n0 + w;

    // ---- Phase 1: edge online-softmax agg (wave per node, bucket CSR) ----
    {
        int deg = cursor[n]; deg = (deg > BUCKET) ? BUCKET : deg;   // >=1 (self-loop)
        const int e0 = n * BUCKET;
        const int e1 = e0 + deg;
        const int elast = e1 - 1;
        float4 xr4;
        {
            uint2 xru = ((const uint2*)(xrh_in + (size_t)n * HD))[l];
            float2 f01 = __half22float2(*reinterpret_cast<__half2*>(&xru.x));
            float2 f23 = __half22float2(*reinterpret_cast<__half2*>(&xru.y));
            xr4.x = f01.x; xr4.y = f01.y; xr4.z = f23.x; xr4.w = f23.y;
        }
        const float4 at4 = ((const float4*)att)[l];
        float m = -1e30f, s = 0.f;
        float4 acc = {0.f, 0.f, 0.f, 0.f};
        uint2 A[4], B[4];
        #pragma unroll
        for (int i = 0; i < 4; ++i) {
            int ee = e0 + i; ee = (ee > elast) ? elast : ee;
            A[i] = ((const uint2*)(xlh_in + (size_t)csr_src[ee] * HD))[l];
        }
        for (int base = e0; base < e1; base += 4) {
            #pragma unroll
            for (int i = 0; i < 4; ++i) {
                int ee = base + 4 + i; ee = (ee > elast) ? elast : ee;
                B[i] = ((const uint2*)(xlh_in + (size_t)csr_src[ee] * HD))[l];
            }
            #pragma unroll
            for (int i = 0; i < 4; ++i) {
                const bool valid = (base + i) < e1;   // wave-uniform
                __half2 h01 = *reinterpret_cast<__half2*>(&A[i].x);
                __half2 h23 = *reinterpret_cast<__half2*>(&A[i].y);
                float2 f01 = __half22float2(h01);
                float2 f23 = __half22float2(h23);
                float c0 = f01.x, c1 = f01.y, c2 = f23.x, c3 = f23.y;
                float z0 = c0 + xr4.x, z1 = c1 + xr4.y, z2 = c2 + xr4.z, z3 = c3 + xr4.w;
                z0 = (z0 > 0.f) ? z0 : 0.2f * z0;
                z1 = (z1 > 0.f) ? z1 : 0.2f * z1;
                z2 = (z2 > 0.f) ? z2 : 0.2f * z2;
                z3 = (z3 > 0.f) ? z3 : 0.2f * z3;
                float p = z0 * at4.x + z1 * at4.y + z2 * at4.z + z3 * at4.w;
                #pragma unroll
                for (int mo = 8; mo; mo >>= 1) p += __shfl_xor(p, mo, 64);
                p = valid ? p : -1e30f;
                float nm = fmaxf(m, p);
                float sc = __expf(m - nm);
                float wv = __expf(p - nm);
                s = s * sc + wv;
                acc.x = acc.x * sc + wv * c0;
                acc.y = acc.y * sc + wv * c1;
                acc.z = acc.z * sc + wv * c2;
                acc.w = acc.w * sc + wv * c3;
                m = nm;
            }
            #pragma unroll
            for (int i = 0; i < 4; ++i) A[i] = B[i];
        }
        const float inv = 1.f / (s + 1e-16f);
        const float4 gb4 = ((const float4*)gbias)[l];
        __half2 o01 = __floats2half2_rn(acc.x * inv + gb4.x, acc.y * inv + gb4.y);
        __half2 o23 = __floats2half2_rn(acc.z * inv + gb4.z, acc.w * inv + gb4.w);
        uint2 outv2;
        outv2.x = *(unsigned int*)&o01;
        outv2.y = *(unsigned int*)&o23;
        ((uint2*)gall_u[w])[l] = outv2;        // g stays in LDS
    }
    __syncthreads();

    // ---- Phase 2: MLP + ACT + proj (4 nodes, dot2, weights shared) ----
    const unsigned int* Wlp = (const unsigned int*)wp;          // [32][256]
    const unsigned int* Wrp = Wlp + 8192;                       // [32][256]
    const unsigned int* W1p = Wlp + 16384;                      // [128][64]
    const unsigned int* W2p = Wlp + 24576;                      // [32][64]

    {
        float acc[4] = {0.f, 0.f, 0.f, 0.f};
        for (int k2 = pp * 32; k2 < pp * 32 + 32; ++k2) {
            unsigned int w2 = W1p[k2 * 64 + d];
            #pragma unroll
            for (int j = 0; j < 4; ++j) acc[j] = dot2(gall_u[j][k2], w2, acc[j]);
        }
        #pragma unroll
        for (int j = 0; j < 4; ++j) part[j][t] = acc[j];
    }
    __syncthreads();
    {
        float v = part[pp][d] + part[pp][64 + d] + part[pp][128 + d] + part[pp][192 + d] + b1[d];
        us_h[pp][d] = __float2half(fmaxf(v, 0.f));
    }
    __syncthreads();
    {
        const unsigned int* us_u = (const unsigned int*)us_h;  // [4][32]
        float acc[4] = {0.f, 0.f, 0.f, 0.f};
        for (int k2 = pp * 8; k2 < pp * 8 + 8; ++k2) {
            unsigned int w2 = W2p[k2 * 64 + d];
            #pragma unroll
            for (int j = 0; j < 4; ++j) acc[j] = dot2(us_u[j * 32 + k2], w2, acc[j]);
        }
        #pragma unroll
        for (int j = 0; j < 4; ++j) part[j][t] = acc[j];
    }
    __syncthreads();
    {
        float hv = part[pp][d] + part[pp][64 + d] + part[pp][128 + d] + part[pp][192 + d] + b2[d];
        hns[pp][d] = hv;
        hns_h[pp][d] = __float2half(hv);
    }
    __syncthreads();
    {
        float p = hns[pp][d] * actW[d];
        #pragma unroll
        for (int mo = 32; mo; mo >>= 1) p += __shfl_xor(p, mo, 64);
        if (d == 0) {
            float term = 1.f / (1.f + __expf(-(p + actB[0])));
            float tot = act_tot[n0 + pp];
            float nt = fminf(tot + term, 1.f);
            float dl = fminf(term, nt - tot);
            act_tot[n0 + pp] = tot + dl;
            delta[pp] = dl;
        }
    }
    __syncthreads();
    final_[(size_t)(n0 + pp) * DIM + d] += delta[pp] * hns[pp][d];

    if (do_proj) {
        const unsigned int* hn_u = (const unsigned int*)hns_h;  // [4][32]
        float al[4] = {0.f, 0.f, 0.f, 0.f}, ar[4] = {0.f, 0.f, 0.f, 0.f};
        for (int k2 = 0; k2 < 32; ++k2) {
            unsigned int wl2 = Wlp[k2 * 256 + t];
            unsigned int wr2 = Wrp[k2 * 256 + t];
            #pragma unroll
            for (int j = 0; j < 4; ++j) {
                unsigned int hh = hn_u[j * 32 + k2];
                al[j] = dot2(hh, wl2, al[j]);
                ar[j] = dot2(hh, wr2, ar[j]);
            }
        }
        float bbl = bl[t], bbr = br[t];
        #pragma unroll
        for (int j = 0; j < 4; ++j) {
            xlh_out[(size_t)(n0 + j) * HD + t] = __float2half(al[j] + bbl);
            xrh_out[(size_t)(n0 + j) * HD + t] = __float2half(ar[j] + bbr);
        }
    }
}

// ---------------- dispatch 8: decoder + log_softmax ----------------
__global__ void decoder_kernel(const float* __restrict__ final_,
                               const float* __restrict__ decW, const float* __restrict__ decB,
                               const int* __restrict__ flags, void* __restrict__ outv) {
    int id = blockIdx.x * 256 + threadIdx.x;
    if (id >= N_NODES * N_PRED * N_CLASS) return;
    int n = id >> 5, r = id & 31, p = r >> 4, c = r & 15;
    float acc = decB[p * N_CLASS + c];
    for (int dd = 0; dd < DIM; ++dd)
        acc += final_[(size_t)n * DIM + dd] * decW[(p * DIM + dd) * N_CLASS + c];
    float mx = acc;
    #pragma unroll
    for (int mo = 8; mo; mo >>= 1) mx = fmaxf(mx, __shfl_xor(mx, mo, 64));
    float ex = __expf(acc - mx);
    float ss = ex;
    #pragma unroll
    for (int mo = 8; mo; mo >>= 1) ss += __shfl_xor(ss, mo, 64);
    float ov = acc - mx - logf(ss);
    int oi = p * (N_NODES * N_CLASS) + n * N_CLASS + c;
    if (flags[1]) ((bf16*)outv)[oi] = __float2bfloat16(ov);
    else          ((float*)outv)[oi] = ov;
}

// ---------------- host launcher ----------------
static size_t align256(size_t x) { return (x + 255) & ~size_t(255); }

extern "C" void kernel_launch(void* const* d_in, const int* in_sizes, int n_in,
                              void* d_out, int out_size, void* d_ws, size_t ws_size,
                              hipStream_t stream) {
    const int* edges = (const int*)d_in[1];

    static const int fids[17] = {0, 2, 3, 4, 5, 6, 7, 8, 9, 10, 11, 12, 13, 14, 15, 16, 17};
    ConvTable tab;
    int cum = 0;
    for (int i = 0; i < 17; ++i) {
        tab.src[i] = d_in[fids[i]];
        tab.start[i] = cum;
        cum += in_sizes[fids[i]];
    }
    tab.start[17] = cum;

    // workspace carve-up (~34 MB)
    char* w = (char*)d_ws;
    size_t o = 0;
    int* flags     = (int*)(w + o); o = align256(o + 16 * sizeof(int));
    int* cursor    = (int*)(w + o); o = align256(o + N_NODES * sizeof(int));
    float* act_tot = (float*)(w + o); o = align256(o + N_NODES * sizeof(float));
    float* final_  = (float*)(w + o); o = align256(o + (size_t)N_NODES * DIM * sizeof(float));
    int* csr_src   = (int*)(w + o); o = align256(o + (size_t)N_NODES * BUCKET * sizeof(int));
    float* xf      = (float*)(w + o); o = align256(o + (size_t)cum * sizeof(float));
    __half* xlh_a  = (__half*)(w + o); o = align256(o + (size_t)N_NODES * HD * sizeof(__half));
    __half* xrh_a  = (__half*)(w + o); o = align256(o + (size_t)N_NODES * HD * sizeof(__half));
    __half* xlh_b  = (__half*)(w + o); o = align256(o + (size_t)N_NODES * HD * sizeof(__half));
    __half* xrh_b  = (__half*)(w + o); o = align256(o + (size_t)N_NODES * HD * sizeof(__half));
    __half* wpack  = (__half*)(w + o); o = align256(o + 53248 * sizeof(__half));
    if (o > ws_size) return;  // diagnostic: zero output => ws too small

    const float* att  = xf + tab.start[7];
    const float* gbias= xf + tab.start[8];
    const float* b1   = xf + tab.start[10];
    const float* b2   = xf + tab.start[12];
    const float* actW = xf + tab.start[13];
    const float* actB = xf + tab.start[14];
    const float* decW = xf + tab.start[15];
    const float* decB = xf + tab.start[16];

    // 1: detect + zero cursor
    detect_kernel<<<(N_NODES + 255) / 256, 256, 0, stream>>>(
        (const unsigned int*)d_in[1], (const unsigned short*)d_in[0], flags, cursor);

    // 2: convert || pack || bucket-scatter
    PreArgs pa;
    pa.tab = tab;
    pa.Wl_raw = d_in[4]; pa.Wr_raw = d_in[6]; pa.W1_raw = d_in[10]; pa.W2_raw = d_in[12];
    pa.edges = edges;
    pa.cb = (cum + 255) / 256;
    pa.pb = (26624 + 255) / 256;
    int sb = (N_E2 + 255) / 256;
    pre_kernel<<<pa.cb + pa.pb + sb, 256, 0, stream>>>(pa, flags, xf, wpack, cursor, csr_src);

    // 3: encoder + proj0 (+zero act/final)
    enc_proj_kernel<<<N_NODES / 8, 256, 0, stream>>>(
        xf, tab.start[0], tab.start[1], tab.start[2],
        tab.start[3], tab.start[4], tab.start[5], tab.start[6],
        xlh_a, xrh_a, act_tot, final_);

    // 4-7: fused universal-transformer steps
    __half* xl_in = xlh_a;  __half* xr_in = xrh_a;
    __half* xl_out = xlh_b; __half* xr_out = xrh_b;
    for (int step = 0; step < N_STEPS; ++step) {
        step_kernel<<<N_NODES / 4, 256, 0, stream>>>(
            xl_in, xr_in, att, gbias, cursor, csr_src, wpack,
            b1, b2, actW, actB,
            xf + tab.start[4], xf + tab.start[6],
            act_tot, final_, xl_out, xr_out, (step < N_STEPS - 1) ? 1 : 0);
        __half* th = xl_in; xl_in = xl_out; xl_out = th;
        __half* tf = xr_in; xr_in = xr_out; xr_out = tf;
    }

    // 8: decoder
    int db = (N_NODES * N_PRED * N_CLASS + 255) / 256;
    decoder_kernel<<<db, 256, 0, stream>>>(final_, decW, decB, flags, d_out);
}